// Round 1
// baseline (286.234 us; speedup 1.0000x reference)
//
#include <hip/hip_runtime.h>
#include <hip/hip_bf16.h>

// channel_cluster_layer: pool -> fc1(sigmoid) -> fc2(sigmoid) -> weighted channel reduce
// B=32, C=2048, L=891 (9*11*9), P=8, HID=8192, NOUT=16384
#define BB 32
#define CC 2048
#define LL 891
#define PP 8
#define HIDN 8192
#define NOUT 16384

typedef __attribute__((ext_vector_type(4))) float f32x4;
typedef __attribute__((ext_vector_type(8))) __bf16 bf16x8;

// ---------- kernel 1: global average pool, one wave per (b,c) row ----------
__global__ __launch_bounds__(256) void pool_kernel(const float* __restrict__ x,
                                                   __hip_bfloat16* __restrict__ pooled) {
  int wid = threadIdx.x >> 6, lane = threadIdx.x & 63;
  int row = blockIdx.x * 4 + wid;  // < 65536
  const float* r = x + (long)row * LL;
  float s = 0.f;
  for (int i = lane; i < LL; i += 64) s += r[i];
#pragma unroll
  for (int off = 32; off > 0; off >>= 1) s += __shfl_xor(s, off);
  if (lane == 0) pooled[row] = __float2bfloat16(s * (1.0f / (float)LL));
}

// ---------- RNE f32 -> bf16 bits ----------
__device__ __forceinline__ unsigned int bfbits(float f) {
  unsigned int x = __builtin_bit_cast(unsigned int, f);
  return (x + 0x7fffu + ((x >> 16) & 1u)) >> 16;
}

// LDS swizzle: rows of 128B, XOR k-byte with (row&7)<<4 (breaks stride-128 bank conflicts)
__device__ __forceinline__ int swz(int row, int kb) {
  return row * 128 + (kb ^ ((row & 7) << 4));
}

// ---------- kernels 2/4: C[32][N] partial = A[32][K](bf16) @ W[N][K](f32->bf16)^T ----------
// grid: (N/64, NSPLIT); block 256 (4 waves). Each wave: one 16-wide n-frag, both m-frags.
__global__ __launch_bounds__(256) void fc_kernel(const __hip_bfloat16* __restrict__ A,
                                                 const float* __restrict__ W,
                                                 float* __restrict__ partial,
                                                 int N, int K, int kc) {
  __shared__ alignas(16) char Al[32 * 128];  // 32 rows x 64 bf16
  __shared__ alignas(16) char Bl[64 * 128];  // 64 rows x 64 bf16
  int tid = threadIdx.x;
  int n0 = blockIdx.x * 64;
  int k0 = blockIdx.y * kc;
  int ar = tid >> 3;                  // A staging: row, 16B chunk (tid&7)
  int br = tid >> 2;                  // B staging: row, 64B f32 chunk (tid&3)
  int bk = (tid & 3) * 16;            // f32 element offset in row
  int lane = tid & 63, wv = tid >> 6;
  int r16 = lane & 15, kg = lane >> 4;

  const __hip_bfloat16* Ap = A + (long)ar * K + k0 + (tid & 7) * 8;
  const float* Wp = W + (long)(n0 + br) * K + k0 + bk;

  f32x4 acc0 = {0.f, 0.f, 0.f, 0.f};
  f32x4 acc1 = {0.f, 0.f, 0.f, 0.f};

  for (int ks = 0; ks < kc; ks += 64) {
    int4 av = *(const int4*)(Ap + ks);
    float4 f0 = *(const float4*)(Wp + ks);
    float4 f1 = *(const float4*)(Wp + ks + 4);
    float4 f2 = *(const float4*)(Wp + ks + 8);
    float4 f3 = *(const float4*)(Wp + ks + 12);
    int4 w0, w1;
    w0.x = (int)(bfbits(f0.x) | (bfbits(f0.y) << 16));
    w0.y = (int)(bfbits(f0.z) | (bfbits(f0.w) << 16));
    w0.z = (int)(bfbits(f1.x) | (bfbits(f1.y) << 16));
    w0.w = (int)(bfbits(f1.z) | (bfbits(f1.w) << 16));
    w1.x = (int)(bfbits(f2.x) | (bfbits(f2.y) << 16));
    w1.y = (int)(bfbits(f2.z) | (bfbits(f2.w) << 16));
    w1.z = (int)(bfbits(f3.x) | (bfbits(f3.y) << 16));
    w1.w = (int)(bfbits(f3.z) | (bfbits(f3.w) << 16));

    __syncthreads();  // previous iteration's frag reads complete
    *(int4*)(Al + swz(ar, (tid & 7) * 16)) = av;
    *(int4*)(Bl + swz(br, (tid & 3) * 32)) = w0;
    *(int4*)(Bl + swz(br, (tid & 3) * 32 + 16)) = w1;
    __syncthreads();

#pragma unroll
    for (int kh = 0; kh < 2; ++kh) {
      int kb = kh * 64 + kg * 16;
      bf16x8 a0 = __builtin_bit_cast(bf16x8, *(const int4*)(Al + swz(r16, kb)));
      bf16x8 a1 = __builtin_bit_cast(bf16x8, *(const int4*)(Al + swz(16 + r16, kb)));
      bf16x8 bv = __builtin_bit_cast(bf16x8, *(const int4*)(Bl + swz(wv * 16 + r16, kb)));
      acc0 = __builtin_amdgcn_mfma_f32_16x16x32_bf16(a0, bv, acc0, 0, 0, 0);
      acc1 = __builtin_amdgcn_mfma_f32_16x16x32_bf16(a1, bv, acc1, 0, 0, 0);
    }
  }

  // C/D layout (m89-verified): col = lane&15, row = (lane>>4)*4 + reg
  long base = (long)blockIdx.y * 32 * N + n0 + wv * 16 + r16;
#pragma unroll
  for (int j = 0; j < 4; ++j) {
    int row = kg * 4 + j;
    partial[base + (long)row * N] = acc0[j];
    partial[base + (long)(row + 16) * N] = acc1[j];
  }
}

// ---------- kernels 3/5: reduce splits + bias + sigmoid ----------
__global__ __launch_bounds__(256) void fc_reduce_kernel(const float* __restrict__ part,
                                                        int nsplit, int MN, int N,
                                                        const float* __restrict__ bias,
                                                        float* __restrict__ outF,
                                                        __hip_bfloat16* __restrict__ outB) {
  int idx = blockIdx.x * 256 + threadIdx.x;
  if (idx >= MN) return;
  float s = 0.f;
  for (int i = 0; i < nsplit; ++i) s += part[(long)i * MN + idx];
  s += bias[idx & (N - 1)];
  float v = 1.f / (1.f + __expf(-s));
  if (outF) outF[idx] = v;
  if (outB) outB[idx] = __float2bfloat16(v);
}

// ---------- kernel 6: weighted[b][p][l] partials = sum_c g[b][p*C+c] * x[b][c][l] ----------
// grid (4 l-blocks, 32 b, 8 c-splits); g values wave-uniform -> scalar loads
__global__ __launch_bounds__(256) void ein_partial_kernel(const float* __restrict__ x,
                                                          const float* __restrict__ g,
                                                          float* __restrict__ part) {
  int l = blockIdx.x * 256 + threadIdx.x;
  int b = blockIdx.y;
  int s = blockIdx.z;
  int c0 = s * 256;
  const float* xp = x + ((long)b * CC + c0) * LL + l;
  const float* gp = g + (long)b * NOUT + c0;
  bool act = l < LL;
  float acc[PP] = {0.f, 0.f, 0.f, 0.f, 0.f, 0.f, 0.f, 0.f};
  for (int i = 0; i < 256; ++i) {
    float xv = act ? xp[(long)i * LL] : 0.f;
#pragma unroll
    for (int p = 0; p < PP; ++p) acc[p] += gp[p * CC + i] * xv;
  }
  if (act) {
    float* pp = part + (long)(s * BB + b) * PP * LL + l;
#pragma unroll
    for (int p = 0; p < PP; ++p) pp[(long)p * LL] = acc[p];
  }
}

// ---------- kernel 7: reduce c-splits, /C ----------
__global__ __launch_bounds__(256) void ein_reduce_kernel(const float* __restrict__ part,
                                                         float* __restrict__ outw) {
  int idx = blockIdx.x * 256 + threadIdx.x;  // < 228096 = 891*256 exactly
  float s = 0.f;
#pragma unroll
  for (int i = 0; i < 8; ++i) s += part[(long)i * (BB * PP * LL) + idx];
  outw[idx] = s * (1.0f / (float)CC);
}

extern "C" void kernel_launch(void* const* d_in, const int* in_sizes, int n_in,
                              void* d_out, int out_size, void* d_ws, size_t ws_size,
                              hipStream_t stream) {
  const float* x     = (const float*)d_in[0];
  const float* fc1_w = (const float*)d_in[1];
  const float* fc1_b = (const float*)d_in[2];
  const float* fc2_w = (const float*)d_in[3];
  const float* fc2_b = (const float*)d_in[4];
  float* out = (float*)d_out;

  char* ws = (char*)d_ws;
  __hip_bfloat16* pooled = (__hip_bfloat16*)ws;              // 32*2048*2   = 128 KB
  __hip_bfloat16* hbuf   = (__hip_bfloat16*)(ws + 131072);   // 32*8192*2   = 512 KB
  float* part            = (float*)(ws + 655360);            // max 8 MB (reused per stage)

  pool_kernel<<<BB * CC / 4, 256, 0, stream>>>(x, pooled);

  fc_kernel<<<dim3(HIDN / 64, 4), 256, 0, stream>>>(pooled, fc1_w, part, HIDN, CC, CC / 4);
  fc_reduce_kernel<<<BB * HIDN / 256, 256, 0, stream>>>(part, 4, BB * HIDN, HIDN, fc1_b,
                                                        nullptr, hbuf);

  fc_kernel<<<dim3(NOUT / 64, 4), 256, 0, stream>>>(hbuf, fc2_w, part, NOUT, HIDN, HIDN / 4);
  fc_reduce_kernel<<<BB * NOUT / 256, 256, 0, stream>>>(part, 4, BB * NOUT, NOUT, fc2_b,
                                                        out, nullptr);

  ein_partial_kernel<<<dim3(4, BB, 8), 256, 0, stream>>>(x, out, part);
  ein_reduce_kernel<<<BB * PP * LL / 256, 256, 0, stream>>>(part, out + BB * PP * CC);
}

// Round 2
// 285.367 us; speedup vs baseline: 1.0030x; 1.0030x over previous
//
#include <hip/hip_runtime.h>
#include <hip/hip_bf16.h>

// channel_cluster_layer: pool -> fc1(sigmoid) -> fc2(sigmoid) -> weighted channel reduce
// B=32, C=2048, L=891 (9*11*9), P=8, HID=8192, NOUT=16384
#define BB 32
#define CC 2048
#define LL 891
#define PP 8
#define HIDN 8192
#define NOUT 16384

typedef __attribute__((ext_vector_type(4))) float f32x4;
typedef __attribute__((ext_vector_type(8))) __bf16 bf16x8;

// ---------- kernel 1: global average pool, one wave per (b,c) row, float4 body ----------
__global__ __launch_bounds__(256) void pool_kernel(const float* __restrict__ x,
                                                   __hip_bfloat16* __restrict__ pooled) {
  int wid = threadIdx.x >> 6, lane = threadIdx.x & 63;
  int row = blockIdx.x * 4 + wid;  // < 65536
  const float* r = x + (long)row * LL;
  // row byte base = row*3564; alignment to 16B cycles with period 4 (891 % 4 == 3)
  int align = (4 - ((row * 3) & 3)) & 3;       // scalar head elements
  int nvec = (LL - align) >> 2;                // float4 count (221 or 222)
  int rem = LL - align - (nvec << 2);          // scalar tail elements
  const float4* v = (const float4*)(r + align);
  float s = 0.f;
  for (int i = lane; i < nvec; i += 64) {
    float4 q = v[i];
    s += (q.x + q.y) + (q.z + q.w);
  }
  if (lane < align) s += r[lane];
  if (lane < rem) s += r[align + (nvec << 2) + lane];
#pragma unroll
  for (int off = 32; off > 0; off >>= 1) s += __shfl_xor(s, off);
  if (lane == 0) pooled[row] = __float2bfloat16(s * (1.0f / (float)LL));
}

// ---------- RNE f32 -> bf16 bits ----------
__device__ __forceinline__ unsigned int bfbits(float f) {
  unsigned int x = __builtin_bit_cast(unsigned int, f);
  return (x + 0x7fffu + ((x >> 16) & 1u)) >> 16;
}

// ---------- kernels 2/4: partial[32][N] = A[32][K](bf16) @ W[N][K](f32->bf16)^T ----------
// Direct-from-global, barrier-free: M=32 means zero B reuse, so LDS staging buys nothing.
// frag layout (matches R0-verified pass): lane holds row (lane&15), k-chunk (lane>>4)*8.
// grid: (N/64, nsplit); block 256 = 4 waves, wave w owns n-rows [bx*64+w*16, +16).
__global__ __launch_bounds__(256) void fc_kernel(const __hip_bfloat16* __restrict__ A,
                                                 const float* __restrict__ W,
                                                 float* __restrict__ partial,
                                                 int N, int K, int kc) {
  int lane = threadIdx.x & 63, wv = threadIdx.x >> 6;
  int n0 = blockIdx.x * 64 + wv * 16;
  int k0 = blockIdx.y * kc;
  int r = lane & 15, kg = lane >> 4;

  const float* Wp = W + (long)(n0 + r) * K + k0 + kg * 8;
  const __hip_bfloat16* Ap0 = A + (long)r * K + k0 + kg * 8;
  const __hip_bfloat16* Ap1 = Ap0 + 16 * (long)K;

  f32x4 acc0 = {0.f, 0.f, 0.f, 0.f};
  f32x4 acc1 = {0.f, 0.f, 0.f, 0.f};

#pragma unroll 2
  for (int ks = 0; ks < kc; ks += 32) {
    float4 w0 = *(const float4*)(Wp + ks);
    float4 w1 = *(const float4*)(Wp + ks + 4);
    int4 a0 = *(const int4*)(Ap0 + ks);
    int4 a1 = *(const int4*)(Ap1 + ks);
    int4 bw;
    bw.x = (int)(bfbits(w0.x) | (bfbits(w0.y) << 16));
    bw.y = (int)(bfbits(w0.z) | (bfbits(w0.w) << 16));
    bw.z = (int)(bfbits(w1.x) | (bfbits(w1.y) << 16));
    bw.w = (int)(bfbits(w1.z) | (bfbits(w1.w) << 16));
    bf16x8 bv = __builtin_bit_cast(bf16x8, bw);
    acc0 = __builtin_amdgcn_mfma_f32_16x16x32_bf16(__builtin_bit_cast(bf16x8, a0), bv, acc0, 0, 0, 0);
    acc1 = __builtin_amdgcn_mfma_f32_16x16x32_bf16(__builtin_bit_cast(bf16x8, a1), bv, acc1, 0, 0, 0);
  }

  // C/D layout (m89-verified): col = lane&15 (-> n), row = (lane>>4)*4 + reg (-> b)
  long base = (long)blockIdx.y * 32 * N + n0 + r;
#pragma unroll
  for (int j = 0; j < 4; ++j) {
    int row = kg * 4 + j;
    partial[base + (long)row * N] = acc0[j];
    partial[base + (long)(row + 16) * N] = acc1[j];
  }
}

// ---------- kernels 3/5: reduce splits + bias + sigmoid ----------
__global__ __launch_bounds__(256) void fc_reduce_kernel(const float* __restrict__ part,
                                                        int nsplit, int MN, int N,
                                                        const float* __restrict__ bias,
                                                        float* __restrict__ outF,
                                                        __hip_bfloat16* __restrict__ outB) {
  int idx = blockIdx.x * 256 + threadIdx.x;
  if (idx >= MN) return;
  float s = 0.f;
  for (int i = 0; i < nsplit; ++i) s += part[(long)i * MN + idx];
  s += bias[idx & (N - 1)];
  float v = 1.f / (1.f + __expf(-s));
  if (outF) outF[idx] = v;
  if (outB) outB[idx] = __float2bfloat16(v);
}

// ---------- kernel 6: weighted[b][p][l] partials = sum_c g[b][p*C+c] * x[b][c][l] ----------
// grid (4 l-blocks, 32 b, 8 c-splits); g values block-uniform -> scalar loads
__global__ __launch_bounds__(256) void ein_partial_kernel(const float* __restrict__ x,
                                                          const float* __restrict__ g,
                                                          float* __restrict__ part) {
  int l = blockIdx.x * 256 + threadIdx.x;
  int b = blockIdx.y;
  int s = blockIdx.z;
  int c0 = s * 256;
  const float* xp = x + ((long)b * CC + c0) * LL + l;
  const float* gp = g + (long)b * NOUT + c0;
  bool act = l < LL;
  float acc[PP] = {0.f, 0.f, 0.f, 0.f, 0.f, 0.f, 0.f, 0.f};
#pragma unroll 4
  for (int i = 0; i < 256; ++i) {
    float xv = act ? xp[(long)i * LL] : 0.f;
#pragma unroll
    for (int p = 0; p < PP; ++p) acc[p] += gp[p * CC + i] * xv;
  }
  if (act) {
    float* pp = part + (long)(s * BB + b) * PP * LL + l;
#pragma unroll
    for (int p = 0; p < PP; ++p) pp[(long)p * LL] = acc[p];
  }
}

// ---------- kernel 7: reduce c-splits, /C ----------
__global__ __launch_bounds__(256) void ein_reduce_kernel(const float* __restrict__ part,
                                                         float* __restrict__ outw) {
  int idx = blockIdx.x * 256 + threadIdx.x;  // 228096 = 891*256 exactly
  float s = 0.f;
#pragma unroll
  for (int i = 0; i < 8; ++i) s += part[(long)i * (BB * PP * LL) + idx];
  outw[idx] = s * (1.0f / (float)CC);
}

extern "C" void kernel_launch(void* const* d_in, const int* in_sizes, int n_in,
                              void* d_out, int out_size, void* d_ws, size_t ws_size,
                              hipStream_t stream) {
  const float* x     = (const float*)d_in[0];
  const float* fc1_w = (const float*)d_in[1];
  const float* fc1_b = (const float*)d_in[2];
  const float* fc2_w = (const float*)d_in[3];
  const float* fc2_b = (const float*)d_in[4];
  float* out = (float*)d_out;

  char* ws = (char*)d_ws;
  __hip_bfloat16* pooled = (__hip_bfloat16*)ws;              // 32*2048*2   = 128 KB
  __hip_bfloat16* hbuf   = (__hip_bfloat16*)(ws + 131072);   // 32*8192*2   = 512 KB
  float* part            = (float*)(ws + 655360);            // max 8 MB (reused per stage)

  pool_kernel<<<BB * CC / 4, 256, 0, stream>>>(x, pooled);

  // fc1: N=8192, K=2048, 8-way split-K (kc=256) -> 1024 blocks
  fc_kernel<<<dim3(HIDN / 64, 8), 256, 0, stream>>>(pooled, fc1_w, part, HIDN, CC, CC / 8);
  fc_reduce_kernel<<<BB * HIDN / 256, 256, 0, stream>>>(part, 8, BB * HIDN, HIDN, fc1_b,
                                                        nullptr, hbuf);

  // fc2: N=16384, K=8192, 4-way split-K (kc=2048) -> 1024 blocks
  fc_kernel<<<dim3(NOUT / 64, 4), 256, 0, stream>>>(hbuf, fc2_w, part, NOUT, HIDN, HIDN / 4);
  fc_reduce_kernel<<<BB * NOUT / 256, 256, 0, stream>>>(part, 4, BB * NOUT, NOUT, fc2_b,
                                                        out, nullptr);

  ein_partial_kernel<<<dim3(4, BB, 8), 256, 0, stream>>>(x, out, part);
  ein_reduce_kernel<<<BB * PP * LL / 256, 256, 0, stream>>>(part, out + BB * PP * CC);
}